// Round 1
// 143.484 us; speedup vs baseline: 1.0195x; 1.0195x over previous
//
#include <hip/hip_runtime.h>
#include <hip/hip_bf16.h>

#define NB 8
#define NS 2048
#define NE 1024
#define ND 64

typedef __attribute__((ext_vector_type(8))) short bf16x8;
typedef __attribute__((ext_vector_type(4))) float f32x4;
typedef unsigned short u16;
typedef unsigned long long u64;

#define MFMA(a, b, c) __builtin_amdgcn_mfma_f32_16x16x32_bf16(a, b, c, 0, 0, 0)

__device__ __forceinline__ u16 f2bf(float f) {
  unsigned int u = __float_as_uint(f);
  u += 0x7fffu + ((u >> 16) & 1u);  // RNE; inputs finite
  return (u16)(u >> 16);
}
__device__ __forceinline__ unsigned cvt2(float a, float b) {  // pack 2 bf16
  __hip_bfloat162 h = __float22bfloat162_rn(float2{a, b});
  return *(unsigned*)&h;
}

// in-place cross-lane half swaps (gfx950): both operands are read+written.
__device__ __forceinline__ void pl32swap(unsigned& a, unsigned& b) {
  asm("v_permlane32_swap_b32 %0, %1" : "+v"(a), "+v"(b));
}
__device__ __forceinline__ void pl16swap(unsigned& a, unsigned& b) {
  asm("v_permlane16_swap_b32 %0, %1" : "+v"(a), "+v"(b));
}

// async copy: each lane 16 B; LDS dst = wave-uniform base + lane*16
__device__ __forceinline__ void alds16(const void* g, void* l) {
  __builtin_amdgcn_global_load_lds(
      (const __attribute__((address_space(1))) unsigned int*)g,
      (__attribute__((address_space(3))) unsigned int*)l, 16, 0, 0);
}

// K0: Wcat2 = bf16 W concat [q|k|v], k-major chunked+swizzled:
// 16-B unit d = c*1536 + n*8 + q', holding row n, k-chunk q = q'^(n&7) of window c.
__global__ void k0_prep(const float* __restrict__ Wq, const float* __restrict__ bq,
                        const float* __restrict__ Wk, const float* __restrict__ bk,
                        const float* __restrict__ Wv, const float* __restrict__ bv,
                        u16* __restrict__ Wcat2, float* __restrict__ bcat,
                        float* __restrict__ vmean) {
  int d = blockIdx.x * 256 + threadIdx.x;  // 24576 units
  int c = d / 1536;
  int rem = d - c * 1536;
  int n = rem >> 3;
  int qp = rem & 7;
  int q = qp ^ (n & 7);
  const float* src = (n < 64) ? (Wq + n * NE) : (n < 128) ? (Wk + (n - 64) * NE)
                                                          : (Wv + (n - 128) * NE);
  const float* sp = src + c * 64 + q * 8;
  float4 a = *(const float4*)sp;
  float4 b = *(const float4*)(sp + 4);
  bf16x8 o;
  o[0] = (short)f2bf(a.x); o[1] = (short)f2bf(a.y);
  o[2] = (short)f2bf(a.z); o[3] = (short)f2bf(a.w);
  o[4] = (short)f2bf(b.x); o[5] = (short)f2bf(b.y);
  o[6] = (short)f2bf(b.z); o[7] = (short)f2bf(b.w);
  *(bf16x8*)&Wcat2[(size_t)d * 8] = o;
  if (blockIdx.x == 0) {
    int t = threadIdx.x;
    if (t < 192) bcat[t] = (t < 64) ? bq[t] : (t < 128) ? bk[t - 64] : bv[t - 128];
    vmean[t] = 0.f;
    vmean[t + 256] = 0.f;
  }
}

// K1: [16384,192] = x*W^T + b. 512 blocks x 256 thr, async dbuf staging, 1 barrier/chunk.
// Epilogue also accumulates vmean[b][d] = mean_s v (atomicAdd, vmean zeroed by k0).
__global__ __launch_bounds__(256) void k1_qkv(
    const float* __restrict__ x, const u16* __restrict__ Wcat2,
    const float* __restrict__ bcat, u16* __restrict__ qb,
    u16* __restrict__ kbf2, u16* __restrict__ vtb2, float* __restrict__ vmean) {
  __shared__ float axs[2][32 * 64];   // 16 KB
  __shared__ u16 bsb[2][192 * 64];    // 48 KB
  const int t = threadIdx.x;
  const int m0 = blockIdx.x * 32;
  const int batch = m0 >> 11;
  const int sl = m0 & (NS - 1);
  const int w = t >> 6;
  const int l = t & 63;
  const int ln = l & 15;
  const int qd = l >> 4;
  const int n0 = w * 48;

  f32x4 zf = {0.f, 0.f, 0.f, 0.f};
  f32x4 acc[2][3] = {{zf, zf, zf}, {zf, zf, zf}};

  auto stageA = [&](int c, int buf) {
    #pragma unroll
    for (int i = 0; i < 2; ++i) {
      int rr = w * 8 + i * 4 + (l >> 4);
      int gch = (l & 15) ^ (rr & 7);
      const float* gp = x + (size_t)(m0 + rr) * NE + c * 64 + gch * 4;
      alds16(gp, &axs[buf][(w * 8 + i * 4) * 64]);
    }
  };
  auto stageB = [&](int c, int buf) {
    const u16* cb = Wcat2 + (size_t)c * 12288;
    #pragma unroll
    for (int i = 0; i < 6; ++i) {
      const u16* gp = cb + (w * 6 + i) * 512 + l * 8;
      alds16(gp, &bsb[buf][(w * 6 + i) * 512]);
    }
  };

  stageA(0, 0);
  stageB(0, 0);

  for (int c = 0; c < 16; ++c) {
    __syncthreads();  // drains buf[c&1] asyncs; prior compute done
    if (c < 15) { stageA(c + 1, (c + 1) & 1); stageB(c + 1, (c + 1) & 1); }
    const int buf = c & 1;
    const int s = ln & 7;
    bf16x8 afr[2][2];
    #pragma unroll
    for (int mi = 0; mi < 2; ++mi) {
      int row = mi * 16 + ln;
      #pragma unroll
      for (int kc = 0; kc < 2; ++kc) {
        int g0 = kc * 8 + qd * 2;
        float4 fa = *(const float4*)&axs[buf][row * 64 + ((g0 ^ s) * 4)];
        float4 fb = *(const float4*)&axs[buf][row * 64 + (((g0 + 1) ^ s) * 4)];
        union { bf16x8 v; unsigned u[4]; } A;
        A.u[0] = cvt2(fa.x, fa.y); A.u[1] = cvt2(fa.z, fa.w);
        A.u[2] = cvt2(fb.x, fb.y); A.u[3] = cvt2(fb.z, fb.w);
        afr[mi][kc] = A.v;
      }
    }
    #pragma unroll
    for (int kc = 0; kc < 2; ++kc)
      #pragma unroll
      for (int nj = 0; nj < 3; ++nj) {
        int n = n0 + nj * 16 + ln;
        bf16x8 bb = *(const bf16x8*)&bsb[buf][n * 64 + (((kc * 4 + qd) ^ s) * 8)];
        acc[0][nj] = MFMA(afr[0][kc], bb, acc[0][nj]);
        acc[1][nj] = MFMA(afr[1][kc], bb, acc[1][nj]);
      }
  }

  // C/D: col = lane&15 (n), row = quad*4 + reg (m)
  #pragma unroll
  for (int nj = 0; nj < 3; ++nj) {
    int n = n0 + nj * 16 + ln;
    float bias = bcat[n];
    #pragma unroll
    for (int mi = 0; mi < 2; ++mi) {
      int jbase = sl + mi * 16 + qd * 4;
      if (n < 64) {
        #pragma unroll
        for (int r = 0; r < 4; ++r)
          qb[((size_t)batch * NS + jbase + r) * ND + n] = f2bf(acc[mi][nj][r] + bias);
      } else if (n < 128) {
        int d = n - 64;
        #pragma unroll
        for (int r = 0; r < 4; ++r) {
          int j = jbase + r;
          int pos = (((d >> 3) ^ (j & 7)) << 3) + (d & 7);
          kbf2[((size_t)batch * NS + j) * ND + pos] = f2bf(acc[mi][nj][r] + bias);
        }
      } else {
        int d = n - 128;
        int off = (jbase & ~63) + (((((jbase >> 5) & 1) ^ ((d >> 2) & 1))) << 5) +
                  (((((jbase >> 3) & 3) ^ (d & 3))) << 3) + (jbase & 7);
        ushort4 sv;
        sv.x = f2bf(acc[mi][nj][0] + bias); sv.y = f2bf(acc[mi][nj][1] + bias);
        sv.z = f2bf(acc[mi][nj][2] + bias); sv.w = f2bf(acc[mi][nj][3] + bias);
        *(ushort4*)&vtb2[((size_t)batch * ND + d) * NS + off] = sv;
      }
    }
    if (n >= 128) {  // vmean partial: this block's 32 rows of column d (wave-uniform)
      float psum = acc[0][nj][0] + acc[0][nj][1] + acc[0][nj][2] + acc[0][nj][3] +
                   acc[1][nj][0] + acc[1][nj][1] + acc[1][nj][2] + acc[1][nj][3] +
                   8.f * bias;
      psum += __shfl_xor(psum, 16);
      psum += __shfl_xor(psum, 32);
      if (l < 16) atomicAdd(&vmean[batch * ND + (n - 128)], psum * (1.f / 2048.f));
    }
  }
}

// K3: MFMA flash attention, NO online max (scores O(3): exp fp32-safe; softmax
// shift-invariant). 512 blocks (8b x 64 tiles x 32 rows, heavy first) x 512 thr
// (8 waves): wave = row-group rg=w&1 (16 rows) x j-group jg=w>>1 (32 j of each
// 128-j chunk). Async dbuf staging, 1 barrier/iter.
// SWAPPED QK^T (MFMA(K,Q)): lane holds S[i=ln][j = jb+16f+4qd+r] -> P formed fully
// in-register via 4x v_cvt_pk_bf16_f32 + 2x permlane32_swap + 2x permlane16_swap
// (no LDS round trip, no lgkmcnt(0) between softmax and PV). Mask folded into exp
// bias via ONE v_lshrrev_b64 per iter; causal compare only in the it==0 body
// (for it>=1 the j-window is provably past the diagonal: jb >= i0+32 > i_max).
__global__ __launch_bounds__(512, 4) void k3_attn(
    const u16* __restrict__ qb, const u16* __restrict__ kbf2,
    const u16* __restrict__ vtb2, const int* __restrict__ mask,
    const float* __restrict__ vmean, float* __restrict__ out) {
  __shared__ u16 ks[2][128 * 64];  // 16 KB each
  __shared__ u16 vs[2][64 * 128];  // 16 KB each (V^T rows d, 128 j)
  __shared__ struct { float mb[2][16][68]; float mlb[2][16]; } ub;  // merge only

  const int g = blockIdx.x;
  const int tl = g >> 3;
  const int b = g & 7;
  const int i0 = tl * 32;
  const int j0f = i0 & ~127;
  const int np = (NS - j0f) >> 7;
  const int t = threadIdx.x;
  const int w = t >> 6;
  const int l = t & 63;
  const int ln = l & 15;
  const int qd = l >> 4;
  const int rg = w & 1;
  const int jg = w >> 1;

  const u16* qp = qb + ((size_t)b * NS + i0 + rg * 16 + ln) * ND + qd * 8;
  bf16x8 aq0 = *(const bf16x8*)qp;
  bf16x8 aq1 = *(const bf16x8*)(qp + 32);

  const u16* kB = kbf2 + (size_t)b * NS * ND;
  const u16* vB = vtb2 + (size_t)b * ND * NS;

  auto stage = [&](int it, int buf) {
    int j0 = j0f + it * 128;
    #pragma unroll
    for (int i = 0; i < 2; ++i) {
      int jl = w * 16 + i * 8;  // K: 8 rows per instr, lane l -> row jl+(l>>3), unit l&7
      alds16(kB + (size_t)(j0 + jl) * ND + l * 8, &ks[buf][jl * 64]);
      int du = w * 2 + i;       // V: 4 d-rows per instr, lane l -> d du*4+(l>>4), unit l&15
      alds16(vB + (size_t)(du * 4 + (l >> 4)) * NS + j0 + (l & 15) * 8,
             &vs[buf][du * 512]);
    }
  };

  f32x4 zf = {0.f, 0.f, 0.f, 0.f};
  f32x4 od[4] = {zf, zf, zf, zf};
  float ls0 = 0.f, ls1 = 0.f;

  stage(0, 0);
  int mval = mask[b * NS + j0f + jg * 32 + (l & 31)];

  for (int it = 0; it < np; ++it) {
    u64 mv = __ballot(mval != 0);  // bit b = mask of j-local (b&31) in this window
    __syncthreads();               // drains buf[it&1] asyncs; prior compute done
    if (it + 1 < np) {
      stage(it + 1, (it + 1) & 1);
      mval = mask[b * NS + j0f + (it + 1) * 128 + jg * 32 + (l & 31)];
    }
    const int buf = it & 1;
    const int jb = j0f + it * 128 + jg * 32;

    // S^T: MFMA(K-rows, Q-rows) -> row (qd*4+r within 16f) = j-local, col (ln) = i
    f32x4 sT[2] = {zf, zf};
    #pragma unroll
    for (int f = 0; f < 2; ++f) {
      const u16* kr = &ks[buf][(jg * 32 + f * 16 + ln) * 64];
      bf16x8 b0 = *(const bf16x8*)&kr[((qd ^ (ln & 7)) * 8)];
      bf16x8 b1 = *(const bf16x8*)&kr[(((4 + qd) ^ (ln & 7)) * 8)];
      sT[f] = MFMA(b0, aq0, sT[f]);
      sT[f] = MFMA(b1, aq1, sT[f]);
    }

    unsigned mq = (unsigned)(mv >> (qd * 4));  // bit (16f+r) = mask of j-local 16f+4qd+r
    float p[2][4];
    if (it == 0) {  // causal boundary can only cross in the first window
      const int di = jb + qd * 4 - (i0 + rg * 16 + ln);  // j-i = di + 16f + r
      #pragma unroll
      for (int f = 0; f < 2; ++f)
        #pragma unroll
        for (int r = 0; r < 4; ++r) {
          bool ok = (((mq >> (16 * f + r)) & 1u) != 0) && (di + 16 * f + r >= 0);
          p[f][r] = ok ? __expf(sT[f][r] * 0.125f) : 0.f;
        }
    } else {
      #pragma unroll
      for (int f = 0; f < 2; ++f)
        #pragma unroll
        for (int r = 0; r < 4; ++r) {
          float bias = ((mq >> (16 * f + r)) & 1u) ? 0.f : -1e30f;
          p[f][r] = __expf(__builtin_fmaf(sT[f][r], 0.125f, bias));
        }
    }
    ls0 += p[0][0] + p[0][1] + p[0][2] + p[0][3];
    ls1 += p[1][0] + p[1][1] + p[1][2] + p[1][3];

    // P -> A-frag in-register. Source word X[f][h]@lane(ln,qd) = j-pair 16f+4qd+2h.
    // Target word e'@lane(ln,qd') = j-pair 8qd'+2e'. 32-swap then 16-swap realizes it.
    unsigned x00 = cvt2(p[0][0], p[0][1]);
    unsigned x01 = cvt2(p[0][2], p[0][3]);
    unsigned x10 = cvt2(p[1][0], p[1][1]);
    unsigned x11 = cvt2(p[1][2], p[1][3]);
    pl32swap(x00, x10);  // x00=[X00@g01,X10@g01]  x10=[X00@g23,X10@g23]
    pl32swap(x01, x11);
    pl16swap(x00, x10);  // x00=E0  x10=E2
    pl16swap(x01, x11);  // x01=E1  x11=E3
    union { bf16x8 v; unsigned u[4]; } PA;
    PA.u[0] = x00; PA.u[1] = x01; PA.u[2] = x10; PA.u[3] = x11;
    bf16x8 pa = PA.v;  // lane(ln,qd): P[i=ln][j = qd*8 .. qd*8+7]

    #pragma unroll
    for (int gx = 0; gx < 4; ++gx) {
      int unit = (jg >> 1) * 8 + (((jg & 1) ^ ((ln >> 2) & 1)) << 2) + (qd ^ (ln & 3));
      bf16x8 bv = *(const bf16x8*)&vs[buf][(gx * 16 + ln) * 128 + unit * 8];
      od[gx] = MFMA(pa, bv, od[gx]);
    }
  }

  // row sums: lane(ln,qd) holds partial for row i=ln over its 8 j's; reduce over qd
  float ls = ls0 + ls1;
  ls += __shfl_xor(ls, 16);
  ls += __shfl_xor(ls, 32);  // all lanes: full stripe sum for row ln

  // additive 4-way jg merge (ub.mb untouched during loop -> no pre-barrier needed)
  #pragma unroll 1
  for (int s = 3; s >= 1; --s) {  // jg s -> s-1
    if (jg == s) {
      #pragma unroll
      for (int r = 0; r < 4; ++r) {
        int row = qd * 4 + r;
        #pragma unroll
        for (int gx = 0; gx < 4; ++gx) ub.mb[rg][row][gx * 16 + ln] = od[gx][r];
      }
      if (qd == 0) ub.mlb[rg][ln] = ls;
    }
    __syncthreads();
    if (jg == s - 1) {
      #pragma unroll
      for (int r = 0; r < 4; ++r) {
        int row = qd * 4 + r;
        #pragma unroll
        for (int gx = 0; gx < 4; ++gx) od[gx][r] += ub.mb[rg][row][gx * 16 + ln];
      }
      ls += ub.mlb[rg][ln];
    }
    __syncthreads();
  }

  if (jg == 0) {
    #pragma unroll
    for (int r = 0; r < 4; ++r) {
      float lr = __shfl(ls, qd * 4 + r);  // transpose ls (row=ln) -> row=qd*4+r
      int row = i0 + rg * 16 + qd * 4 + r;
      float* orow = out + ((size_t)b * NS + row) * ND;
      if (lr > 0.f) {
        float inv = 1.f / lr;
        #pragma unroll
        for (int gx = 0; gx < 4; ++gx) orow[gx * 16 + ln] = od[gx][r] * inv;
      } else {  // all-invalid row: reference softmax uniform over all j
        #pragma unroll
        for (int gx = 0; gx < 4; ++gx) orow[gx * 16 + ln] = vmean[b * ND + gx * 16 + ln];
      }
    }
  }
}

extern "C" void kernel_launch(void* const* d_in, const int* in_sizes, int n_in,
                              void* d_out, int out_size, void* d_ws, size_t ws_size,
                              hipStream_t stream) {
  (void)in_sizes; (void)n_in; (void)out_size; (void)ws_size;
  const float* x = (const float*)d_in[0];
  const int* mask = (const int*)d_in[1];
  const float* Wq = (const float*)d_in[2];
  const float* bq = (const float*)d_in[3];
  const float* Wk = (const float*)d_in[4];
  const float* bk = (const float*)d_in[5];
  const float* Wv = (const float*)d_in[6];
  const float* bv = (const float*)d_in[7];
  float* out = (float*)d_out;

  char* ws = (char*)d_ws;
  u16* Wcat2 = (u16*)ws;                  // 384 KB
  float* bcat = (float*)(ws + 393216);    // 768 B
  float* vmean = (float*)(ws + 394240);   // 2 KB
  u16* qb = (u16*)(ws + (1u << 20));      // 2 MB bf16 [b][s][d]
  u16* kbf2 = (u16*)(ws + (3u << 20));    // 2 MB bf16 [b][s][d] swizzled
  u16* vtb2 = (u16*)(ws + (5u << 20));    // 2 MB bf16 [b][d][s] swizzled

  hipLaunchKernelGGL(k0_prep, dim3(96), dim3(256), 0, stream,
                     Wq, bq, Wk, bk, Wv, bv, Wcat2, bcat, vmean);
  hipLaunchKernelGGL(k1_qkv, dim3(512), dim3(256), 0, stream,
                     x, Wcat2, bcat, qb, kbf2, vtb2, vmean);
  hipLaunchKernelGGL(k3_attn, dim3(512), dim3(512), 0, stream,
                     qb, kbf2, vtb2, mask, vmean, out);
}

// Round 2
// 140.369 us; speedup vs baseline: 1.0421x; 1.0222x over previous
//
#include <hip/hip_runtime.h>
#include <hip/hip_bf16.h>

#define NB 8
#define NS 2048
#define NE 1024
#define ND 64

typedef __attribute__((ext_vector_type(8))) short bf16x8;
typedef __attribute__((ext_vector_type(4))) float f32x4;
typedef unsigned short u16;
typedef unsigned long long u64;

#define MFMA(a, b, c) __builtin_amdgcn_mfma_f32_16x16x32_bf16(a, b, c, 0, 0, 0)

__device__ __forceinline__ u16 f2bf(float f) {
  unsigned int u = __float_as_uint(f);
  u += 0x7fffu + ((u >> 16) & 1u);  // RNE; inputs finite
  return (u16)(u >> 16);
}
__device__ __forceinline__ unsigned cvt2(float a, float b) {  // pack 2 bf16
  __hip_bfloat162 h = __float22bfloat162_rn(float2{a, b});
  return *(unsigned*)&h;
}

// in-place cross-lane half swaps (gfx950): both operands are read+written.
__device__ __forceinline__ void pl32swap(unsigned& a, unsigned& b) {
  asm("v_permlane32_swap_b32 %0, %1" : "+v"(a), "+v"(b));
}
__device__ __forceinline__ void pl16swap(unsigned& a, unsigned& b) {
  asm("v_permlane16_swap_b32 %0, %1" : "+v"(a), "+v"(b));
}

// async copy: each lane 16 B; LDS dst = wave-uniform base + lane*16
__device__ __forceinline__ void alds16(const void* g, void* l) {
  __builtin_amdgcn_global_load_lds(
      (const __attribute__((address_space(1))) unsigned int*)g,
      (__attribute__((address_space(3))) unsigned int*)l, 16, 0, 0);
}

// K0: Wcat2 = bf16 W concat [q|k|v], k-major chunked+swizzled:
// 16-B unit d = c*1536 + n*8 + q', holding row n, k-chunk q = q'^(n&7) of window c.
__global__ void k0_prep(const float* __restrict__ Wq, const float* __restrict__ bq,
                        const float* __restrict__ Wk, const float* __restrict__ bk,
                        const float* __restrict__ Wv, const float* __restrict__ bv,
                        u16* __restrict__ Wcat2, float* __restrict__ bcat,
                        float* __restrict__ vmean) {
  int d = blockIdx.x * 256 + threadIdx.x;  // 24576 units
  int c = d / 1536;
  int rem = d - c * 1536;
  int n = rem >> 3;
  int qp = rem & 7;
  int q = qp ^ (n & 7);
  const float* src = (n < 64) ? (Wq + n * NE) : (n < 128) ? (Wk + (n - 64) * NE)
                                                          : (Wv + (n - 128) * NE);
  const float* sp = src + c * 64 + q * 8;
  float4 a = *(const float4*)sp;
  float4 b = *(const float4*)(sp + 4);
  bf16x8 o;
  o[0] = (short)f2bf(a.x); o[1] = (short)f2bf(a.y);
  o[2] = (short)f2bf(a.z); o[3] = (short)f2bf(a.w);
  o[4] = (short)f2bf(b.x); o[5] = (short)f2bf(b.y);
  o[6] = (short)f2bf(b.z); o[7] = (short)f2bf(b.w);
  *(bf16x8*)&Wcat2[(size_t)d * 8] = o;
  if (blockIdx.x == 0) {
    int t = threadIdx.x;
    if (t < 192) bcat[t] = (t < 64) ? bq[t] : (t < 128) ? bk[t - 64] : bv[t - 128];
    vmean[t] = 0.f;
    vmean[t + 256] = 0.f;
  }
}

// K1: [16384,192] = x*W^T + b. 256 blocks x 512 thr (8 waves = 2 m-groups x 4
// n-groups), 64 rows/block: B chunk staged ONCE per 64 rows (halves Wcat2 L2
// restage vs 32-row blocks), async dbuf staging, 1 barrier/chunk. Epilogue also
// accumulates vmean[b][d] = mean_s v (atomicAdd, vmean zeroed by k0).
__global__ __launch_bounds__(512) void k1_qkv(
    const float* __restrict__ x, const u16* __restrict__ Wcat2,
    const float* __restrict__ bcat, u16* __restrict__ qb,
    u16* __restrict__ kbf2, u16* __restrict__ vtb2, float* __restrict__ vmean) {
  __shared__ float axs[2][64 * 64];   // 32 KB
  __shared__ u16 bsb[2][192 * 64];    // 48 KB
  const int t = threadIdx.x;
  const int m0 = blockIdx.x * 64;
  const int batch = m0 >> 11;
  const int sl = m0 & (NS - 1);
  const int w = t >> 6;    // 0..7
  const int l = t & 63;
  const int ln = l & 15;
  const int qd = l >> 4;
  const int mg = w & 1;    // row-group: 32 rows
  const int n0 = (w >> 1) * 48;  // n-group: 48 cols

  f32x4 zf = {0.f, 0.f, 0.f, 0.f};
  f32x4 acc[2][3] = {{zf, zf, zf}, {zf, zf, zf}};

  auto stageA = [&](int c, int buf) {
    #pragma unroll
    for (int i = 0; i < 2; ++i) {
      int rr = w * 8 + i * 4 + (l >> 4);      // 8 waves x 8 rows = 64 rows
      int gch = (l & 15) ^ (rr & 7);
      const float* gp = x + (size_t)(m0 + rr) * NE + c * 64 + gch * 4;
      alds16(gp, &axs[buf][(w * 8 + i * 4) * 64]);
    }
  };
  auto stageB = [&](int c, int buf) {
    const u16* cb = Wcat2 + (size_t)c * 12288;
    #pragma unroll
    for (int i = 0; i < 3; ++i) {            // 8 waves x 3 = 24 units of 512 u16
      const u16* gp = cb + (w * 3 + i) * 512 + l * 8;
      alds16(gp, &bsb[buf][(w * 3 + i) * 512]);
    }
  };

  stageA(0, 0);
  stageB(0, 0);

  for (int c = 0; c < 16; ++c) {
    __syncthreads();  // drains buf[c&1] asyncs; prior compute done
    if (c < 15) { stageA(c + 1, (c + 1) & 1); stageB(c + 1, (c + 1) & 1); }
    const int buf = c & 1;
    const int s = ln & 7;
    bf16x8 afr[2][2];
    #pragma unroll
    for (int mi = 0; mi < 2; ++mi) {
      int row = mg * 32 + mi * 16 + ln;
      #pragma unroll
      for (int kc = 0; kc < 2; ++kc) {
        int g0 = kc * 8 + qd * 2;
        float4 fa = *(const float4*)&axs[buf][row * 64 + ((g0 ^ s) * 4)];
        float4 fb = *(const float4*)&axs[buf][row * 64 + (((g0 + 1) ^ s) * 4)];
        union { bf16x8 v; unsigned u[4]; } A;
        A.u[0] = cvt2(fa.x, fa.y); A.u[1] = cvt2(fa.z, fa.w);
        A.u[2] = cvt2(fb.x, fb.y); A.u[3] = cvt2(fb.z, fb.w);
        afr[mi][kc] = A.v;
      }
    }
    #pragma unroll
    for (int kc = 0; kc < 2; ++kc)
      #pragma unroll
      for (int nj = 0; nj < 3; ++nj) {
        int n = n0 + nj * 16 + ln;
        bf16x8 bb = *(const bf16x8*)&bsb[buf][n * 64 + (((kc * 4 + qd) ^ s) * 8)];
        acc[0][nj] = MFMA(afr[0][kc], bb, acc[0][nj]);
        acc[1][nj] = MFMA(afr[1][kc], bb, acc[1][nj]);
      }
  }

  // C/D: col = lane&15 (n), row = quad*4 + reg (m)
  #pragma unroll
  for (int nj = 0; nj < 3; ++nj) {
    int n = n0 + nj * 16 + ln;
    float bias = bcat[n];
    #pragma unroll
    for (int mi = 0; mi < 2; ++mi) {
      int jbase = sl + mg * 32 + mi * 16 + qd * 4;
      if (n < 64) {
        #pragma unroll
        for (int r = 0; r < 4; ++r)
          qb[((size_t)batch * NS + jbase + r) * ND + n] = f2bf(acc[mi][nj][r] + bias);
      } else if (n < 128) {
        int d = n - 64;
        #pragma unroll
        for (int r = 0; r < 4; ++r) {
          int j = jbase + r;
          int pos = (((d >> 3) ^ (j & 7)) << 3) + (d & 7);
          kbf2[((size_t)batch * NS + j) * ND + pos] = f2bf(acc[mi][nj][r] + bias);
        }
      } else {
        int d = n - 128;
        int off = (jbase & ~63) + (((((jbase >> 5) & 1) ^ ((d >> 2) & 1))) << 5) +
                  (((((jbase >> 3) & 3) ^ (d & 3))) << 3) + (jbase & 7);
        ushort4 sv;
        sv.x = f2bf(acc[mi][nj][0] + bias); sv.y = f2bf(acc[mi][nj][1] + bias);
        sv.z = f2bf(acc[mi][nj][2] + bias); sv.w = f2bf(acc[mi][nj][3] + bias);
        *(ushort4*)&vtb2[((size_t)batch * ND + d) * NS + off] = sv;
      }
    }
    if (n >= 128) {  // vmean partial: this wave's 32 rows of column d (wave-uniform)
      float psum = acc[0][nj][0] + acc[0][nj][1] + acc[0][nj][2] + acc[0][nj][3] +
                   acc[1][nj][0] + acc[1][nj][1] + acc[1][nj][2] + acc[1][nj][3] +
                   8.f * bias;
      psum += __shfl_xor(psum, 16);
      psum += __shfl_xor(psum, 32);
      if (l < 16) atomicAdd(&vmean[batch * ND + (n - 128)], psum * (1.f / 2048.f));
    }
  }
}

// K3: MFMA flash attention, NO online max (scores O(3): exp fp32-safe; softmax
// shift-invariant). 512 blocks (8b x 64 tiles x 32 rows, heavy first) x 512 thr
// (8 waves): wave = row-group rg=w&1 (16 rows) x j-group jg=w>>1 (32 j of each
// 128-j chunk). Async dbuf staging, 1 barrier/iter.
// SWAPPED QK^T (MFMA(K,Q)): lane holds S[i=ln][j = jb+16f+4qd+r] -> P formed fully
// in-register via 4x v_cvt_pk_bf16_f32 + 2x permlane32_swap + 2x permlane16_swap
// (no LDS round trip, no lgkmcnt(0) between softmax and PV). Mask folded into exp
// bias via ONE v_lshrrev_b64 per iter; causal compare only in the it==0 body
// (for it>=1 the j-window is provably past the diagonal: jb >= i0+32 > i_max).
__global__ __launch_bounds__(512, 4) void k3_attn(
    const u16* __restrict__ qb, const u16* __restrict__ kbf2,
    const u16* __restrict__ vtb2, const int* __restrict__ mask,
    const float* __restrict__ vmean, float* __restrict__ out) {
  __shared__ u16 ks[2][128 * 64];  // 16 KB each
  __shared__ u16 vs[2][64 * 128];  // 16 KB each (V^T rows d, 128 j)
  __shared__ struct { float mb[2][16][68]; float mlb[2][16]; } ub;  // merge only

  const int g = blockIdx.x;
  const int tl = g >> 3;
  const int b = g & 7;
  const int i0 = tl * 32;
  const int j0f = i0 & ~127;
  const int np = (NS - j0f) >> 7;
  const int t = threadIdx.x;
  const int w = t >> 6;
  const int l = t & 63;
  const int ln = l & 15;
  const int qd = l >> 4;
  const int rg = w & 1;
  const int jg = w >> 1;

  const u16* qp = qb + ((size_t)b * NS + i0 + rg * 16 + ln) * ND + qd * 8;
  bf16x8 aq0 = *(const bf16x8*)qp;
  bf16x8 aq1 = *(const bf16x8*)(qp + 32);

  const u16* kB = kbf2 + (size_t)b * NS * ND;
  const u16* vB = vtb2 + (size_t)b * ND * NS;

  auto stage = [&](int it, int buf) {
    int j0 = j0f + it * 128;
    #pragma unroll
    for (int i = 0; i < 2; ++i) {
      int jl = w * 16 + i * 8;  // K: 8 rows per instr, lane l -> row jl+(l>>3), unit l&7
      alds16(kB + (size_t)(j0 + jl) * ND + l * 8, &ks[buf][jl * 64]);
      int du = w * 2 + i;       // V: 4 d-rows per instr, lane l -> d du*4+(l>>4), unit l&15
      alds16(vB + (size_t)(du * 4 + (l >> 4)) * NS + j0 + (l & 15) * 8,
             &vs[buf][du * 512]);
    }
  };

  f32x4 zf = {0.f, 0.f, 0.f, 0.f};
  f32x4 od[4] = {zf, zf, zf, zf};
  float ls0 = 0.f, ls1 = 0.f;

  stage(0, 0);
  int mval = mask[b * NS + j0f + jg * 32 + (l & 31)];

  for (int it = 0; it < np; ++it) {
    u64 mv = __ballot(mval != 0);  // bit b = mask of j-local (b&31) in this window
    __syncthreads();               // drains buf[it&1] asyncs; prior compute done
    if (it + 1 < np) {
      stage(it + 1, (it + 1) & 1);
      mval = mask[b * NS + j0f + (it + 1) * 128 + jg * 32 + (l & 31)];
    }
    const int buf = it & 1;
    const int jb = j0f + it * 128 + jg * 32;

    // S^T: MFMA(K-rows, Q-rows) -> row (qd*4+r within 16f) = j-local, col (ln) = i
    f32x4 sT[2] = {zf, zf};
    #pragma unroll
    for (int f = 0; f < 2; ++f) {
      const u16* kr = &ks[buf][(jg * 32 + f * 16 + ln) * 64];
      bf16x8 b0 = *(const bf16x8*)&kr[((qd ^ (ln & 7)) * 8)];
      bf16x8 b1 = *(const bf16x8*)&kr[(((4 + qd) ^ (ln & 7)) * 8)];
      sT[f] = MFMA(b0, aq0, sT[f]);
      sT[f] = MFMA(b1, aq1, sT[f]);
    }

    unsigned mq = (unsigned)(mv >> (qd * 4));  // bit (16f+r) = mask of j-local 16f+4qd+r
    float p[2][4];
    if (it == 0) {  // causal boundary can only cross in the first window
      const int di = jb + qd * 4 - (i0 + rg * 16 + ln);  // j-i = di + 16f + r
      #pragma unroll
      for (int f = 0; f < 2; ++f)
        #pragma unroll
        for (int r = 0; r < 4; ++r) {
          bool ok = (((mq >> (16 * f + r)) & 1u) != 0) && (di + 16 * f + r >= 0);
          p[f][r] = ok ? __expf(sT[f][r] * 0.125f) : 0.f;
        }
    } else {
      #pragma unroll
      for (int f = 0; f < 2; ++f)
        #pragma unroll
        for (int r = 0; r < 4; ++r) {
          float bias = ((mq >> (16 * f + r)) & 1u) ? 0.f : -1e30f;
          p[f][r] = __expf(__builtin_fmaf(sT[f][r], 0.125f, bias));
        }
    }
    ls0 += p[0][0] + p[0][1] + p[0][2] + p[0][3];
    ls1 += p[1][0] + p[1][1] + p[1][2] + p[1][3];

    // P -> A-frag in-register. Source word X[f][h]@lane(ln,qd) = j-pair 16f+4qd+2h.
    // Target word e'@lane(ln,qd') = j-pair 8qd'+2e'. 32-swap then 16-swap realizes it.
    unsigned x00 = cvt2(p[0][0], p[0][1]);
    unsigned x01 = cvt2(p[0][2], p[0][3]);
    unsigned x10 = cvt2(p[1][0], p[1][1]);
    unsigned x11 = cvt2(p[1][2], p[1][3]);
    pl32swap(x00, x10);  // x00=[X00@g01,X10@g01]  x10=[X00@g23,X10@g23]
    pl32swap(x01, x11);
    pl16swap(x00, x10);  // x00=E0  x10=E2
    pl16swap(x01, x11);  // x01=E1  x11=E3
    union { bf16x8 v; unsigned u[4]; } PA;
    PA.u[0] = x00; PA.u[1] = x01; PA.u[2] = x10; PA.u[3] = x11;
    bf16x8 pa = PA.v;  // lane(ln,qd): P[i=ln][j = qd*8 .. qd*8+7]

    #pragma unroll
    for (int gx = 0; gx < 4; ++gx) {
      int unit = (jg >> 1) * 8 + (((jg & 1) ^ ((ln >> 2) & 1)) << 2) + (qd ^ (ln & 3));
      bf16x8 bv = *(const bf16x8*)&vs[buf][(gx * 16 + ln) * 128 + unit * 8];
      od[gx] = MFMA(pa, bv, od[gx]);
    }
  }

  // row sums: lane(ln,qd) holds partial for row i=ln over its 8 j's; reduce over qd
  float ls = ls0 + ls1;
  ls += __shfl_xor(ls, 16);
  ls += __shfl_xor(ls, 32);  // all lanes: full stripe sum for row ln

  // additive 4-way jg merge (ub.mb untouched during loop -> no pre-barrier needed)
  #pragma unroll 1
  for (int s = 3; s >= 1; --s) {  // jg s -> s-1
    if (jg == s) {
      #pragma unroll
      for (int r = 0; r < 4; ++r) {
        int row = qd * 4 + r;
        #pragma unroll
        for (int gx = 0; gx < 4; ++gx) ub.mb[rg][row][gx * 16 + ln] = od[gx][r];
      }
      if (qd == 0) ub.mlb[rg][ln] = ls;
    }
    __syncthreads();
    if (jg == s - 1) {
      #pragma unroll
      for (int r = 0; r < 4; ++r) {
        int row = qd * 4 + r;
        #pragma unroll
        for (int gx = 0; gx < 4; ++gx) od[gx][r] += ub.mb[rg][row][gx * 16 + ln];
      }
      ls += ub.mlb[rg][ln];
    }
    __syncthreads();
  }

  if (jg == 0) {
    #pragma unroll
    for (int r = 0; r < 4; ++r) {
      float lr = __shfl(ls, qd * 4 + r);  // transpose ls (row=ln) -> row=qd*4+r
      int row = i0 + rg * 16 + qd * 4 + r;
      float* orow = out + ((size_t)b * NS + row) * ND;
      if (lr > 0.f) {
        float inv = 1.f / lr;
        #pragma unroll
        for (int gx = 0; gx < 4; ++gx) orow[gx * 16 + ln] = od[gx][r] * inv;
      } else {  // all-invalid row: reference softmax uniform over all j
        #pragma unroll
        for (int gx = 0; gx < 4; ++gx) orow[gx * 16 + ln] = vmean[b * ND + gx * 16 + ln];
      }
    }
  }
}

extern "C" void kernel_launch(void* const* d_in, const int* in_sizes, int n_in,
                              void* d_out, int out_size, void* d_ws, size_t ws_size,
                              hipStream_t stream) {
  (void)in_sizes; (void)n_in; (void)out_size; (void)ws_size;
  const float* x = (const float*)d_in[0];
  const int* mask = (const int*)d_in[1];
  const float* Wq = (const float*)d_in[2];
  const float* bq = (const float*)d_in[3];
  const float* Wk = (const float*)d_in[4];
  const float* bk = (const float*)d_in[5];
  const float* Wv = (const float*)d_in[6];
  const float* bv = (const float*)d_in[7];
  float* out = (float*)d_out;

  char* ws = (char*)d_ws;
  u16* Wcat2 = (u16*)ws;                  // 384 KB
  float* bcat = (float*)(ws + 393216);    // 768 B
  float* vmean = (float*)(ws + 394240);   // 2 KB
  u16* qb = (u16*)(ws + (1u << 20));      // 2 MB bf16 [b][s][d]
  u16* kbf2 = (u16*)(ws + (3u << 20));    // 2 MB bf16 [b][s][d] swizzled
  u16* vtb2 = (u16*)(ws + (5u << 20));    // 2 MB bf16 [b][d][s] swizzled

  hipLaunchKernelGGL(k0_prep, dim3(96), dim3(256), 0, stream,
                     Wq, bq, Wk, bk, Wv, bv, Wcat2, bcat, vmean);
  hipLaunchKernelGGL(k1_qkv, dim3(256), dim3(512), 0, stream,
                     x, Wcat2, bcat, qb, kbf2, vtb2, vmean);
  hipLaunchKernelGGL(k3_attn, dim3(512), dim3(512), 0, stream,
                     qb, kbf2, vtb2, mask, vmean, out);
}